// Round 4
// baseline (880.755 us; speedup 1.0000x reference)
//
#include <hip/hip_runtime.h>
#include <stdint.h>

#define N_TOKENS  8192
#define D_MODEL   1024
#define D_FF      4096
#define TOP_K     2
#define N_EXPERTS 8
#define TOTAL_SLOTS (N_TOKENS * TOP_K)   // 16384
#define CAP       4096                    // 2.0 * 16384 / 8
#define ROWS_PAD  (TOTAL_SLOTS + 384)     // pad so 256-row tile staging never reads OOB

typedef unsigned short u16;
typedef __attribute__((ext_vector_type(4))) float f32x4;
typedef __attribute__((ext_vector_type(8))) short bf16x8;

__device__ __forceinline__ float bf2f(u16 u) {
  union { unsigned int i; float f; } v; v.i = ((unsigned int)u) << 16; return v.f;
}
__device__ __forceinline__ u16 f2bf(float f) {
  union { float f; unsigned int i; } v; v.f = f;
  unsigned int u = v.i;
  return (u16)((u + 0x7FFFu + ((u >> 16) & 1u)) >> 16);  // RN-even
}

// async global->LDS, 16B per lane; LDS dest is wave-uniform base + lane*16
__device__ __forceinline__ void gld_lds16(const void* g, void* l) {
  __builtin_amdgcn_global_load_lds(
      (const __attribute__((address_space(1))) unsigned int*)g,
      (__attribute__((address_space(3))) unsigned int*)l,
      16, 0, 0);
}

// ---------------------------------------------------------------------------
// Routing: deterministic stable counting sort of slots by expert.
// info[0..7] = placed counts (clamped at CAP), info[8..15] = segment starts,
// info[16] = total placed rows.
// ---------------------------------------------------------------------------
__global__ __launch_bounds__(256) void k_route(const int* __restrict__ eidx,
                                               int* __restrict__ info,
                                               int* __restrict__ row_of_slot,
                                               int* __restrict__ tok_of_row) {
  __shared__ int s_total[N_EXPERTS];
  __shared__ int s_start[N_EXPERTS];
  __shared__ int s_base[N_EXPERTS];
  __shared__ int s_wcnt[4][N_EXPERTS];
  const int t = threadIdx.x;
  const int lane = t & 63;
  const int w = t >> 6;

  if (t < N_EXPERTS) { s_total[t] = 0; s_base[t] = 0; }
  __syncthreads();

  for (int c = 0; c < TOTAL_SLOTS / 256; ++c) {
    int e = eidx[c * 256 + t];
    atomicAdd(&s_total[e], 1);
  }
  __syncthreads();

  if (t == 0) {
    int off = 0;
    for (int e = 0; e < N_EXPERTS; ++e) {
      int placed = s_total[e] < CAP ? s_total[e] : CAP;
      s_start[e] = off;
      info[e] = placed;
      info[N_EXPERTS + e] = off;
      off += placed;
    }
    info[2 * N_EXPERTS] = off;
  }
  __syncthreads();

  for (int c = 0; c < TOTAL_SLOTS / 256; ++c) {
    int s = c * 256 + t;
    int e = eidx[s];
    unsigned long long mymask = 0;
    for (int ee = 0; ee < N_EXPERTS; ++ee) {
      unsigned long long m = __ballot(e == ee);
      if (ee == e) mymask = m;
      if (lane == 0) s_wcnt[w][ee] = __popcll(m);
    }
    int rank_in_wave = __popcll(mymask & ((1ULL << lane) - 1ULL));
    __syncthreads();
    int prior = 0;
    for (int ww = 0; ww < w; ++ww) prior += s_wcnt[ww][e];
    int pos = s_base[e] + prior + rank_in_wave;
    int row = (pos < CAP) ? (s_start[e] + pos) : -1;
    row_of_slot[s] = row;
    if (row >= 0) tok_of_row[row] = s >> 1;   // token = slot / TOP_K
    __syncthreads();
    if (t < N_EXPERTS) {
      int tot = 0;
      for (int ww = 0; ww < 4; ++ww) tot += s_wcnt[ww][t];
      s_base[t] += tot;
    }
    __syncthreads();
  }
}

// ---------------------------------------------------------------------------
// Per-expert transpose + fp32->bf16: in [R][C] fp32 -> out row `remap(c)` of
// a [*][R] bf16 matrix. MODE 0: plain (w3). MODE 1/2: interleave W1/W2 cols
// into W12t: ffcol c -> row (c>>5)*64 + (MODE==2?32:0) + (c&31).
// ---------------------------------------------------------------------------
template<int MODE, int OSTRIDE>
__global__ __launch_bounds__(256) void k_transpose(const float* __restrict__ in,
                                                   u16* __restrict__ out,
                                                   int R, int C) {
  __shared__ float tile[64][65];
  const int e = blockIdx.z;
  in  += (size_t)e * R * C;
  out += (size_t)e * OSTRIDE;
  const int c0 = blockIdx.x * 64;
  const int r0 = blockIdx.y * 64;
  const int tx = threadIdx.x & 15, ty = threadIdx.x >> 4;

  #pragma unroll
  for (int rr = 0; rr < 4; ++rr) {
    int r = ty + rr * 16;
    float4 v = *(const float4*)&in[(size_t)(r0 + r) * C + c0 + tx * 4];
    tile[r][tx * 4 + 0] = v.x; tile[r][tx * 4 + 1] = v.y;
    tile[r][tx * 4 + 2] = v.z; tile[r][tx * 4 + 3] = v.w;
  }
  __syncthreads();
  #pragma unroll
  for (int rr = 0; rr < 4; ++rr) {
    int oc = ty + rr * 16;
    ushort4 o;
    o.x = f2bf(tile[tx * 4 + 0][oc]);
    o.y = f2bf(tile[tx * 4 + 1][oc]);
    o.z = f2bf(tile[tx * 4 + 2][oc]);
    o.w = f2bf(tile[tx * 4 + 3][oc]);
    int c = c0 + oc;
    size_t orow = (MODE == 0) ? (size_t)c
                              : (size_t)(c >> 5) * 64 + (MODE == 2 ? 32 : 0) + (c & 31);
    *(ushort4*)&out[orow * R + r0 + tx * 4] = o;
  }
}

// ---------------------------------------------------------------------------
// Gather dispatched rows of x into compacted bf16 matrix Xd [ROWS_PAD][D_MODEL]
// ---------------------------------------------------------------------------
__global__ __launch_bounds__(256) void k_dispatch(const float* __restrict__ x,
                                                  const int* __restrict__ tok_of_row,
                                                  const int* __restrict__ info,
                                                  u16* __restrict__ Xd) {
  const int r = blockIdx.x;
  const int t = threadIdx.x;
  const int total = info[2 * N_EXPERTS];
  if (r >= total) {
    ushort4 z = {0, 0, 0, 0};
    *(ushort4*)&Xd[(size_t)r * D_MODEL + t * 4] = z;
    return;
  }
  int tok = tok_of_row[r];
  float4 v = *(const float4*)&x[(size_t)tok * D_MODEL + t * 4];
  ushort4 o;
  o.x = f2bf(v.x); o.y = f2bf(v.y); o.z = f2bf(v.z); o.w = f2bf(v.w);
  *(ushort4*)&Xd[(size_t)r * D_MODEL + t * 4] = o;
}

// ---------------------------------------------------------------------------
// 4-phase counted-vmcnt grouped GEMM: C = A @ B^T per expert segment.
// BM=BN=256, BK=64, 512 thr = 8 waves (2M x 4N). Per-wave out 128x64.
// LDS [2 dbuf][2 K-half][256 rows][32 cols] per matrix = 128 KiB total.
// Phases = (kk, m-half) quadrants, 16 MFMA each. B-frags (4 reads) load at
// P0/P2 and PERSIST through P1/P3 -> 24 ds_read_b128 per K-tile per wave
// (8/4/8/4), vs 40 in the failed R3 (N-half) decomposition.
// Stage order (tile t+1, into nbuf): P0:Ah0 P1:Bh0 P2:Ah1 P3:Bh1 (2 loads ea).
// vmcnt(4) before barriers of P0 (needs t-1's Ah0,Bh0: 8->4 outstanding) and
// P2 (needs t-1's Ah1,Bh1: 8->4). Never drains to 0 in the loop (T4).
// Intra-row chunk XOR slot = c ^ ((r>>1)&3): 2-way-max bank aliasing (free);
// source-side pre-swizzle (rule 21: linear LDS dest, swizzled global src).
// DUAL (ffn1): B is W12t (gate/value col-interleaved per 64-row group) so
// acc[m][n<2] = gate, acc[m][n+2] = value for the SAME ff-col ->
// thread-local SwiGLU epilogue.
// ---------------------------------------------------------------------------
template<int K, int NB, bool DUAL>
__global__ __launch_bounds__(512, 2) void k_gemm8(const u16* __restrict__ A,
                                                  const u16* __restrict__ B,
                                                  u16* __restrict__ OUT,
                                                  const int* __restrict__ info) {
  const int e = blockIdx.z;
  const int count = info[e];
  const int row0 = blockIdx.y * 256;
  if (row0 >= count) return;
  const int start = info[N_EXPERTS + e];
  const int col0 = blockIdx.x * 256;

  __shared__ u16 lsA[2][2][256 * 32];
  __shared__ u16 lsB[2][2][256 * 32];

  const int tid = threadIdx.x;
  const int lane = tid & 63, wid = tid >> 6;
  const int wm = wid >> 2, wn = wid & 3;
  const int l15 = lane & 15;
  const int aslot = (lane >> 4) ^ ((l15 >> 1) & 3);   // read-side chunk slot

  const u16* gA = A + (size_t)(start + row0) * K;
  const u16* gB = B + ((size_t)e * NB + col0) * K;

  f32x4 acc[8][4] = {};

  auto stageA = [&](int kt, int h, int bufi) {
    const int koff = kt * 64 + h * 32;
    #pragma unroll
    for (int j = 0; j < 2; ++j) {
      const int q = j * 8 + wid;
      const int r = q * 16 + (lane >> 2);
      const int c = (lane & 3) ^ ((r >> 1) & 3);      // inverse-swizzled source
      gld_lds16(gA + (size_t)r * K + koff + c * 8, (void*)&lsA[bufi][h][q * 512]);
    }
  };
  auto stageB = [&](int kt, int h, int bufi) {
    const int koff = kt * 64 + h * 32;
    #pragma unroll
    for (int j = 0; j < 2; ++j) {
      const int q = j * 8 + wid;
      const int r = q * 16 + (lane >> 2);
      const int c = (lane & 3) ^ ((r >> 1) & 3);
      gld_lds16(gB + (size_t)r * K + koff + c * 8, (void*)&lsB[bufi][h][q * 512]);
    }
  };

  // PHASE(HALF=kk, MH=m-half, LOADB, VM, STAGE): see ledger in header comment.
#define PHASE(HALF, MH, LOADB, VM, STAGE_STMT)                                 \
  do {                                                                         \
    if (VM) asm volatile("s_waitcnt vmcnt(4)" ::: "memory");                   \
    asm volatile("s_barrier" ::: "memory");                                    \
    const u16* bApt = &lsA[buf][HALF][0];                                      \
    const u16* bBpt = &lsB[buf][HALF][0];                                      \
    bf16x8 a[4];                                                               \
    _Pragma("unroll")                                                          \
    for (int m = 0; m < 4; ++m)                                                \
      a[m] = *(const bf16x8*)&bApt[(wm * 128 + (MH * 4 + m) * 16 + l15) * 32 + aslot * 8]; \
    if (LOADB) {                                                               \
      _Pragma("unroll")                                                        \
      for (int n = 0; n < 4; ++n)                                              \
        bb[n] = *(const bf16x8*)&bBpt[(wn * 64 + n * 16 + l15) * 32 + aslot * 8]; \
    }                                                                          \
    STAGE_STMT;                                                                \
    __builtin_amdgcn_s_setprio(1);                                             \
    _Pragma("unroll")                                                          \
    for (int m = 0; m < 4; ++m) {                                              \
      _Pragma("unroll")                                                        \
      for (int n = 0; n < 4; ++n)                                              \
        acc[MH * 4 + m][n] = __builtin_amdgcn_mfma_f32_16x16x32_bf16(a[m], bb[n], acc[MH * 4 + m][n], 0, 0, 0); \
    }                                                                          \
    __builtin_amdgcn_s_setprio(0);                                             \
  } while (0)

  // prologue: K-tile 0 into dbuf 0 (stage order = steady-state order)
  stageA(0, 0, 0); stageB(0, 0, 0); stageA(0, 1, 0); stageB(0, 1, 0);

  constexpr int NT = K / 64;
  for (int t = 0; t < NT; ++t) {
    const int buf = t & 1, nbuf = buf ^ 1;
    const int tn = (t + 1 < NT) ? (t + 1) : t;   // clamped prefetch (data never read)
    bf16x8 bb[4];
    PHASE(0, 0, true,  true,  stageA(tn, 0, nbuf));
    PHASE(0, 1, false, false, stageB(tn, 0, nbuf));
    PHASE(1, 0, true,  true,  stageA(tn, 1, nbuf));
    PHASE(1, 1, false, false, stageB(tn, 1, nbuf));
  }
  asm volatile("s_waitcnt vmcnt(0)" ::: "memory");
#undef PHASE

  const int rmax = count - row0;
  const size_t obase = (size_t)(start + row0);
  if (DUAL) {
    // interleaved col group: g = col0/64 + wn; ff-col = g*32 + n*16 + l15
    const int ffbase = ((col0 >> 6) + wn) * 32 + l15;
    #pragma unroll
    for (int m = 0; m < 8; ++m) {
      #pragma unroll
      for (int j = 0; j < 4; ++j) {
        int rit = wm * 128 + m * 16 + (lane >> 4) * 4 + j;
        if (rit < rmax) {
          #pragma unroll
          for (int n = 0; n < 2; ++n) {
            float g = acc[m][n][j];
            float v = acc[m][n + 2][j];
            float h = g * v / (1.0f + __expf(-g));   // silu(g)*v
            OUT[(obase + rit) * D_FF + ffbase + n * 16] = f2bf(h);
          }
        }
      }
    }
  } else {
    #pragma unroll
    for (int m = 0; m < 8; ++m) {
      #pragma unroll
      for (int j = 0; j < 4; ++j) {
        int rit = wm * 128 + m * 16 + (lane >> 4) * 4 + j;
        if (rit < rmax) {
          #pragma unroll
          for (int n = 0; n < 4; ++n)
            OUT[(obase + rit) * D_MODEL + col0 + wn * 64 + n * 16 + l15] = f2bf(acc[m][n][j]);
        }
      }
    }
  }
}

// ---------------------------------------------------------------------------
// Combine: out[t] = sum_k w[t,k] * Y[row(t,k)]   (deterministic k order)
// ---------------------------------------------------------------------------
__global__ __launch_bounds__(256) void k_combine(const u16* __restrict__ Y,
                                                 const int* __restrict__ row_of_slot,
                                                 const float* __restrict__ ew,
                                                 float* __restrict__ out) {
  const int tok = blockIdx.x;
  const int c = threadIdx.x * 4;
  const int r0 = row_of_slot[tok * 2 + 0];
  const int r1 = row_of_slot[tok * 2 + 1];
  const float w0 = ew[tok * 2 + 0];
  const float w1 = ew[tok * 2 + 1];
  float a0 = 0.f, a1 = 0.f, a2 = 0.f, a3 = 0.f;
  if (r0 >= 0) {
    ushort4 y = *(const ushort4*)&Y[(size_t)r0 * D_MODEL + c];
    a0 = w0 * bf2f(y.x); a1 = w0 * bf2f(y.y); a2 = w0 * bf2f(y.z); a3 = w0 * bf2f(y.w);
  }
  if (r1 >= 0) {
    ushort4 y = *(const ushort4*)&Y[(size_t)r1 * D_MODEL + c];
    a0 += w1 * bf2f(y.x); a1 += w1 * bf2f(y.y); a2 += w1 * bf2f(y.z); a3 += w1 * bf2f(y.w);
  }
  float4 o; o.x = a0; o.y = a1; o.z = a2; o.w = a3;
  *(float4*)&out[(size_t)tok * D_MODEL + c] = o;
}

// ---------------------------------------------------------------------------
extern "C" void kernel_launch(void* const* d_in, const int* in_sizes, int n_in,
                              void* d_out, int out_size, void* d_ws, size_t ws_size,
                              hipStream_t stream) {
  const float* x  = (const float*)d_in[0];
  const int*   ei = (const int*)d_in[1];
  const float* ew = (const float*)d_in[2];
  const float* w1 = (const float*)d_in[3];
  const float* w2 = (const float*)d_in[4];
  const float* w3 = (const float*)d_in[5];
  float* out = (float*)d_out;

  char* ws = (char*)d_ws;
  size_t off = 0;
  auto alloc = [&](size_t b) { char* p = ws + off; off += (b + 255) & ~(size_t)255; return p; };
  int* info        = (int*)alloc(256);
  int* row_of_slot = (int*)alloc(sizeof(int) * TOTAL_SLOTS);
  int* tok_of_row  = (int*)alloc(sizeof(int) * ROWS_PAD);
  u16* Xd   = (u16*)alloc((size_t)2 * ROWS_PAD * D_MODEL);
  u16* W12t = (u16*)alloc((size_t)2 * N_EXPERTS * 2 * D_FF * D_MODEL);  // interleaved, N'=8192
  u16* W3t  = (u16*)alloc((size_t)2 * N_EXPERTS * D_FF * D_MODEL);
  u16* H    = (u16*)alloc((size_t)2 * ROWS_PAD * D_FF);
  u16* Y    = (u16*)alloc((size_t)2 * ROWS_PAD * D_MODEL);

  k_route<<<1, 256, 0, stream>>>(ei, info, row_of_slot, tok_of_row);
  k_transpose<1, 2 * D_FF * D_MODEL><<<dim3(D_FF / 64, D_MODEL / 64, N_EXPERTS), 256, 0, stream>>>(w1, W12t, D_MODEL, D_FF);
  k_transpose<2, 2 * D_FF * D_MODEL><<<dim3(D_FF / 64, D_MODEL / 64, N_EXPERTS), 256, 0, stream>>>(w2, W12t, D_MODEL, D_FF);
  k_transpose<0, D_FF * D_MODEL><<<dim3(D_MODEL / 64, D_FF / 64, N_EXPERTS), 256, 0, stream>>>(w3, W3t, D_FF, D_MODEL);
  k_dispatch<<<ROWS_PAD, 256, 0, stream>>>(x, tok_of_row, info, Xd);
  k_gemm8<D_MODEL, 2 * D_FF, true><<<dim3(2 * D_FF / 256, CAP / 256, N_EXPERTS), 512, 0, stream>>>(Xd, W12t, H, info);
  k_gemm8<D_FF, D_MODEL, false><<<dim3(D_MODEL / 256, CAP / 256, N_EXPERTS), 512, 0, stream>>>(H, W3t, Y, info);
  k_combine<<<N_TOKENS, 256, 0, stream>>>(Y, row_of_slot, ew, out);
}

// Round 6
// 782.776 us; speedup vs baseline: 1.1252x; 1.1252x over previous
//
#include <hip/hip_runtime.h>
#include <stdint.h>

#define N_TOKENS  8192
#define D_MODEL   1024
#define D_FF      4096
#define TOP_K     2
#define N_EXPERTS 8
#define TOTAL_SLOTS (N_TOKENS * TOP_K)   // 16384
#define CAP       4096                    // 2.0 * 16384 / 8
#define ROWS_PAD  (TOTAL_SLOTS + 128)     // pad so tile staging never reads OOB

typedef unsigned short u16;
typedef __attribute__((ext_vector_type(4))) float f32x4;
typedef __attribute__((ext_vector_type(8))) short bf16x8;

__device__ __forceinline__ float bf2f(u16 u) {
  union { unsigned int i; float f; } v; v.i = ((unsigned int)u) << 16; return v.f;
}
__device__ __forceinline__ u16 f2bf(float f) {
  union { float f; unsigned int i; } v; v.f = f;
  unsigned int u = v.i;
  return (u16)((u + 0x7FFFu + ((u >> 16) & 1u)) >> 16);  // RN-even
}

// async global->LDS, 16B per lane; LDS dest is wave-uniform base + lane*16
__device__ __forceinline__ void gld_lds16(const void* g, void* l) {
  __builtin_amdgcn_global_load_lds(
      (const __attribute__((address_space(1))) unsigned int*)g,
      (__attribute__((address_space(3))) unsigned int*)l,
      16, 0, 0);
}

// ---------------------------------------------------------------------------
// Routing: deterministic stable counting sort of slots by expert.
// ---------------------------------------------------------------------------
__global__ __launch_bounds__(256) void k_route(const int* __restrict__ eidx,
                                               int* __restrict__ info,
                                               int* __restrict__ row_of_slot,
                                               int* __restrict__ tok_of_row) {
  __shared__ int s_total[N_EXPERTS];
  __shared__ int s_start[N_EXPERTS];
  __shared__ int s_base[N_EXPERTS];
  __shared__ int s_wcnt[4][N_EXPERTS];
  const int t = threadIdx.x;
  const int lane = t & 63;
  const int w = t >> 6;

  if (t < N_EXPERTS) { s_total[t] = 0; s_base[t] = 0; }
  __syncthreads();

  for (int c = 0; c < TOTAL_SLOTS / 256; ++c) {
    int e = eidx[c * 256 + t];
    atomicAdd(&s_total[e], 1);
  }
  __syncthreads();

  if (t == 0) {
    int off = 0;
    for (int e = 0; e < N_EXPERTS; ++e) {
      int placed = s_total[e] < CAP ? s_total[e] : CAP;
      s_start[e] = off;
      info[e] = placed;
      info[N_EXPERTS + e] = off;
      off += placed;
    }
    info[2 * N_EXPERTS] = off;
  }
  __syncthreads();

  for (int c = 0; c < TOTAL_SLOTS / 256; ++c) {
    int s = c * 256 + t;
    int e = eidx[s];
    unsigned long long mymask = 0;
    for (int ee = 0; ee < N_EXPERTS; ++ee) {
      unsigned long long m = __ballot(e == ee);
      if (ee == e) mymask = m;
      if (lane == 0) s_wcnt[w][ee] = __popcll(m);
    }
    int rank_in_wave = __popcll(mymask & ((1ULL << lane) - 1ULL));
    __syncthreads();
    int prior = 0;
    for (int ww = 0; ww < w; ++ww) prior += s_wcnt[ww][e];
    int pos = s_base[e] + prior + rank_in_wave;
    int row = (pos < CAP) ? (s_start[e] + pos) : -1;
    row_of_slot[s] = row;
    if (row >= 0) tok_of_row[row] = s >> 1;   // token = slot / TOP_K
    __syncthreads();
    if (t < N_EXPERTS) {
      int tot = 0;
      for (int ww = 0; ww < 4; ++ww) tot += s_wcnt[ww][t];
      s_base[t] += tot;
    }
    __syncthreads();
  }
}

// ---------------------------------------------------------------------------
// Per-expert transpose + fp32->bf16: in [R][C] fp32 -> out [C][R] bf16
// ---------------------------------------------------------------------------
__global__ __launch_bounds__(256) void k_transpose(const float* __restrict__ in,
                                                   u16* __restrict__ out,
                                                   int R, int C) {
  __shared__ float tile[64][65];
  const int e = blockIdx.z;
  in  += (size_t)e * R * C;
  out += (size_t)e * R * C;
  const int c0 = blockIdx.x * 64;
  const int r0 = blockIdx.y * 64;
  const int tx = threadIdx.x & 15, ty = threadIdx.x >> 4;

  #pragma unroll
  for (int rr = 0; rr < 4; ++rr) {
    int r = ty + rr * 16;
    float4 v = *(const float4*)&in[(size_t)(r0 + r) * C + c0 + tx * 4];
    tile[r][tx * 4 + 0] = v.x; tile[r][tx * 4 + 1] = v.y;
    tile[r][tx * 4 + 2] = v.z; tile[r][tx * 4 + 3] = v.w;
  }
  __syncthreads();
  #pragma unroll
  for (int rr = 0; rr < 4; ++rr) {
    int oc = ty + rr * 16;
    ushort4 o;
    o.x = f2bf(tile[tx * 4 + 0][oc]);
    o.y = f2bf(tile[tx * 4 + 1][oc]);
    o.z = f2bf(tile[tx * 4 + 2][oc]);
    o.w = f2bf(tile[tx * 4 + 3][oc]);
    *(ushort4*)&out[(size_t)(c0 + oc) * R + r0 + tx * 4] = o;
  }
}

// ---------------------------------------------------------------------------
// Gather dispatched rows of x into compacted bf16 matrix Xd [ROWS_PAD][D_MODEL]
// ---------------------------------------------------------------------------
__global__ __launch_bounds__(256) void k_dispatch(const float* __restrict__ x,
                                                  const int* __restrict__ tok_of_row,
                                                  const int* __restrict__ info,
                                                  u16* __restrict__ Xd) {
  const int r = blockIdx.x;
  const int t = threadIdx.x;
  const int total = info[2 * N_EXPERTS];
  if (r >= total) {
    ushort4 z = {0, 0, 0, 0};
    *(ushort4*)&Xd[(size_t)r * D_MODEL + t * 4] = z;
    return;
  }
  int tok = tok_of_row[r];
  float4 v = *(const float4*)&x[(size_t)tok * D_MODEL + t * 4];
  ushort4 o;
  o.x = f2bf(v.x); o.y = f2bf(v.y); o.z = f2bf(v.z); o.w = f2bf(v.w);
  *(ushort4*)&Xd[(size_t)r * D_MODEL + t * 4] = o;
}

// ---------------------------------------------------------------------------
// FFN pass 1 (fused gate+value): H = silu(Xd @ w1) * (Xd @ w2), bf16 out.
// R2-verbatim (known good): 128x128 tile, BK=64, 4 waves (2x2),
// 16x16x32 bf16 MFMA, global_load_lds staging, XOR chunk swizzle
// (read slot = chunk ^ (row&7), pre-swizzled global source; rule 21).
// ---------------------------------------------------------------------------
__global__ __launch_bounds__(256, 2) void k_ffn1(const u16* __restrict__ Xd,
                                                 const u16* __restrict__ W1t,
                                                 const u16* __restrict__ W2t,
                                                 u16* __restrict__ H,
                                                 const int* __restrict__ info) {
  const int e = blockIdx.z;
  const int count = info[e];
  const int row0 = blockIdx.y * 128;
  if (row0 >= count) return;
  const int start = info[N_EXPERTS + e];
  const int col0 = blockIdx.x * 128;

  __shared__ u16 lsA[128 * 64];
  __shared__ u16 lsB1[128 * 64];
  __shared__ u16 lsB2[128 * 64];

  const int t = threadIdx.x, lane = t & 63, wid = t >> 6;
  const int wr = wid >> 1, wc = wid & 1;

  const u16* gA  = Xd  + (size_t)(start + row0) * D_MODEL;
  const u16* gB1 = W1t + (size_t)e * D_FF * D_MODEL + (size_t)col0 * D_MODEL;
  const u16* gB2 = W2t + (size_t)e * D_FF * D_MODEL + (size_t)col0 * D_MODEL;

  f32x4 accG[4][4] = {};
  f32x4 accV[4][4] = {};

  const int srow = wid * 8 + (lane >> 3);                       // + i*32
  const int skk  = (((lane & 7) ^ ((lane >> 3) & 7)) * 8);
  const int rk0 = (((0 * 4 + (lane >> 4)) ^ (lane & 7)) * 8);   // kk=0
  const int rk1 = (((1 * 4 + (lane >> 4)) ^ (lane & 7)) * 8);   // kk=1

  for (int k0 = 0; k0 < D_MODEL; k0 += 64) {
    __syncthreads();
    #pragma unroll
    for (int i = 0; i < 4; ++i) {
      int r = i * 32 + srow;
      int lbase = (i * 32 + wid * 8) * 64;
      gld_lds16(gA  + (size_t)r * D_MODEL + k0 + skk, &lsA[lbase]);
      gld_lds16(gB1 + (size_t)r * D_MODEL + k0 + skk, &lsB1[lbase]);
      gld_lds16(gB2 + (size_t)r * D_MODEL + k0 + skk, &lsB2[lbase]);
    }
    __syncthreads();   // drains vmcnt -> tiles ready
    #pragma unroll
    for (int kk = 0; kk < 2; ++kk) {
      const int rk = kk ? rk1 : rk0;
      bf16x8 a[4];
      #pragma unroll
      for (int m = 0; m < 4; ++m)
        a[m] = *(const bf16x8*)&lsA[(wr * 64 + m * 16 + (lane & 15)) * 64 + rk];
      #pragma unroll
      for (int n = 0; n < 4; ++n) {
        bf16x8 b1 = *(const bf16x8*)&lsB1[(wc * 64 + n * 16 + (lane & 15)) * 64 + rk];
        bf16x8 b2 = *(const bf16x8*)&lsB2[(wc * 64 + n * 16 + (lane & 15)) * 64 + rk];
        #pragma unroll
        for (int m = 0; m < 4; ++m) {
          accG[m][n] = __builtin_amdgcn_mfma_f32_16x16x32_bf16(a[m], b1, accG[m][n], 0, 0, 0);
          accV[m][n] = __builtin_amdgcn_mfma_f32_16x16x32_bf16(a[m], b2, accV[m][n], 0, 0, 0);
        }
      }
    }
  }

  const int rmax = count - row0;
  const size_t hbase = (size_t)(start + row0);
  #pragma unroll
  for (int m = 0; m < 4; ++m) {
    #pragma unroll
    for (int j = 0; j < 4; ++j) {
      int rit = wr * 64 + m * 16 + (lane >> 4) * 4 + j;  // D: row=(lane>>4)*4+reg
      if (rit < rmax) {
        #pragma unroll
        for (int n = 0; n < 4; ++n) {
          float g = accG[m][n][j];
          float v = accV[m][n][j];
          float h = g * v / (1.0f + __expf(-g));   // silu(g)*v
          H[(hbase + rit) * D_FF + col0 + wc * 64 + n * 16 + (lane & 15)] = f2bf(h);
        }
      }
    }
  }
}

// ---------------------------------------------------------------------------
// FFN pass 2, wide-col: Y = H @ w3 (B^T layout). Structural CLONE of k_ffn1:
// 128 rows x 256 cols per block (B1 = cols col0..+127, B2 = cols col0+128..
// +255 of W3t), BK=64, 4 waves, same staging/swizzle/barrier pattern.
// A-tile staged once, reused for both col-halves -> 64 MFMA per 12 staging
// loads per K-step (same ratio as k_ffn1, vs 32:8 in the old k_ffn2).
// ---------------------------------------------------------------------------
__global__ __launch_bounds__(256, 2) void k_ffn2w(const u16* __restrict__ Hbuf,
                                                  const u16* __restrict__ W3t,
                                                  u16* __restrict__ Y,
                                                  const int* __restrict__ info) {
  const int e = blockIdx.z;
  const int count = info[e];
  const int row0 = blockIdx.y * 128;
  if (row0 >= count) return;
  const int start = info[N_EXPERTS + e];
  const int col0 = blockIdx.x * 256;

  __shared__ u16 lsA[128 * 64];
  __shared__ u16 lsB1[128 * 64];
  __shared__ u16 lsB2[128 * 64];

  const int t = threadIdx.x, lane = t & 63, wid = t >> 6;
  const int wr = wid >> 1, wc = wid & 1;

  const u16* gA  = Hbuf + (size_t)(start + row0) * D_FF;
  const u16* gB1 = W3t + ((size_t)e * D_MODEL + col0) * D_FF;
  const u16* gB2 = gB1 + (size_t)128 * D_FF;

  f32x4 acc1[4][4] = {};
  f32x4 acc2[4][4] = {};

  const int srow = wid * 8 + (lane >> 3);                       // + i*32
  const int skk  = (((lane & 7) ^ ((lane >> 3) & 7)) * 8);
  const int rk0 = (((0 * 4 + (lane >> 4)) ^ (lane & 7)) * 8);   // kk=0
  const int rk1 = (((1 * 4 + (lane >> 4)) ^ (lane & 7)) * 8);   // kk=1

  for (int k0 = 0; k0 < D_FF; k0 += 64) {
    __syncthreads();
    #pragma unroll
    for (int i = 0; i < 4; ++i) {
      int r = i * 32 + srow;
      int lbase = (i * 32 + wid * 8) * 64;
      gld_lds16(gA  + (size_t)r * D_FF + k0 + skk, &lsA[lbase]);
      gld_lds16(gB1 + (size_t)r * D_FF + k0 + skk, &lsB1[lbase]);
      gld_lds16(gB2 + (size_t)r * D_FF + k0 + skk, &lsB2[lbase]);
    }
    __syncthreads();   // drains vmcnt -> tiles ready
    #pragma unroll
    for (int kk = 0; kk < 2; ++kk) {
      const int rk = kk ? rk1 : rk0;
      bf16x8 a[4];
      #pragma unroll
      for (int m = 0; m < 4; ++m)
        a[m] = *(const bf16x8*)&lsA[(wr * 64 + m * 16 + (lane & 15)) * 64 + rk];
      #pragma unroll
      for (int n = 0; n < 4; ++n) {
        bf16x8 b1 = *(const bf16x8*)&lsB1[(wc * 64 + n * 16 + (lane & 15)) * 64 + rk];
        bf16x8 b2 = *(const bf16x8*)&lsB2[(wc * 64 + n * 16 + (lane & 15)) * 64 + rk];
        #pragma unroll
        for (int m = 0; m < 4; ++m) {
          acc1[m][n] = __builtin_amdgcn_mfma_f32_16x16x32_bf16(a[m], b1, acc1[m][n], 0, 0, 0);
          acc2[m][n] = __builtin_amdgcn_mfma_f32_16x16x32_bf16(a[m], b2, acc2[m][n], 0, 0, 0);
        }
      }
    }
  }

  const int rmax = count - row0;
  const size_t ybase = (size_t)(start + row0);
  #pragma unroll
  for (int m = 0; m < 4; ++m) {
    #pragma unroll
    for (int j = 0; j < 4; ++j) {
      int rit = wr * 64 + m * 16 + (lane >> 4) * 4 + j;
      if (rit < rmax) {
        #pragma unroll
        for (int n = 0; n < 4; ++n) {
          int c = col0 + wc * 64 + n * 16 + (lane & 15);
          Y[(ybase + rit) * D_MODEL + c]       = f2bf(acc1[m][n][j]);
          Y[(ybase + rit) * D_MODEL + c + 128] = f2bf(acc2[m][n][j]);
        }
      }
    }
  }
}

// ---------------------------------------------------------------------------
// Combine: out[t] = sum_k w[t,k] * Y[row(t,k)]   (deterministic k order)
// ---------------------------------------------------------------------------
__global__ __launch_bounds__(256) void k_combine(const u16* __restrict__ Y,
                                                 const int* __restrict__ row_of_slot,
                                                 const float* __restrict__ ew,
                                                 float* __restrict__ out) {
  const int tok = blockIdx.x;
  const int c = threadIdx.x * 4;
  const int r0 = row_of_slot[tok * 2 + 0];
  const int r1 = row_of_slot[tok * 2 + 1];
  const float w0 = ew[tok * 2 + 0];
  const float w1 = ew[tok * 2 + 1];
  float a0 = 0.f, a1 = 0.f, a2 = 0.f, a3 = 0.f;
  if (r0 >= 0) {
    ushort4 y = *(const ushort4*)&Y[(size_t)r0 * D_MODEL + c];
    a0 = w0 * bf2f(y.x); a1 = w0 * bf2f(y.y); a2 = w0 * bf2f(y.z); a3 = w0 * bf2f(y.w);
  }
  if (r1 >= 0) {
    ushort4 y = *(const ushort4*)&Y[(size_t)r1 * D_MODEL + c];
    a0 += w1 * bf2f(y.x); a1 += w1 * bf2f(y.y); a2 += w1 * bf2f(y.z); a3 += w1 * bf2f(y.w);
  }
  float4 o; o.x = a0; o.y = a1; o.z = a2; o.w = a3;
  *(float4*)&out[(size_t)tok * D_MODEL + c] = o;
}

// ---------------------------------------------------------------------------
extern "C" void kernel_launch(void* const* d_in, const int* in_sizes, int n_in,
                              void* d_out, int out_size, void* d_ws, size_t ws_size,
                              hipStream_t stream) {
  const float* x  = (const float*)d_in[0];
  const int*   ei = (const int*)d_in[1];
  const float* ew = (const float*)d_in[2];
  const float* w1 = (const float*)d_in[3];
  const float* w2 = (const float*)d_in[4];
  const float* w3 = (const float*)d_in[5];
  float* out = (float*)d_out;

  char* ws = (char*)d_ws;
  size_t off = 0;
  auto alloc = [&](size_t b) { char* p = ws + off; off += (b + 255) & ~(size_t)255; return p; };
  int* info        = (int*)alloc(256);
  int* row_of_slot = (int*)alloc(sizeof(int) * TOTAL_SLOTS);
  int* tok_of_row  = (int*)alloc(sizeof(int) * ROWS_PAD);
  u16* Xd  = (u16*)alloc((size_t)2 * ROWS_PAD * D_MODEL);
  u16* W1t = (u16*)alloc((size_t)2 * N_EXPERTS * D_FF * D_MODEL);
  u16* W2t = (u16*)alloc((size_t)2 * N_EXPERTS * D_FF * D_MODEL);
  u16* W3t = (u16*)alloc((size_t)2 * N_EXPERTS * D_FF * D_MODEL);
  u16* H   = (u16*)alloc((size_t)2 * ROWS_PAD * D_FF);
  u16* Y   = (u16*)alloc((size_t)2 * ROWS_PAD * D_MODEL);

  k_route<<<1, 256, 0, stream>>>(ei, info, row_of_slot, tok_of_row);
  k_transpose<<<dim3(D_FF / 64, D_MODEL / 64, N_EXPERTS), 256, 0, stream>>>(w1, W1t, D_MODEL, D_FF);
  k_transpose<<<dim3(D_FF / 64, D_MODEL / 64, N_EXPERTS), 256, 0, stream>>>(w2, W2t, D_MODEL, D_FF);
  k_transpose<<<dim3(D_MODEL / 64, D_FF / 64, N_EXPERTS), 256, 0, stream>>>(w3, W3t, D_FF, D_MODEL);
  k_dispatch<<<ROWS_PAD, 256, 0, stream>>>(x, tok_of_row, info, Xd);
  k_ffn1<<<dim3(D_FF / 128, CAP / 128, N_EXPERTS), 256, 0, stream>>>(Xd, W1t, W2t, H, info);
  k_ffn2w<<<dim3(D_MODEL / 256, CAP / 128, N_EXPERTS), 256, 0, stream>>>(H, W3t, Y, info);
  k_combine<<<N_TOKENS, 256, 0, stream>>>(Y, row_of_slot, ew, out);
}

// Round 7
// 691.069 us; speedup vs baseline: 1.2745x; 1.1327x over previous
//
#include <hip/hip_runtime.h>
#include <stdint.h>

#define N_TOKENS  8192
#define D_MODEL   1024
#define D_FF      4096
#define TOP_K     2
#define N_EXPERTS 8
#define TOTAL_SLOTS (N_TOKENS * TOP_K)   // 16384
#define CAP       4096                    // 2.0 * 16384 / 8
#define ROWS_PAD  (TOTAL_SLOTS + 128)     // pad so tile staging never reads OOB

typedef unsigned short u16;
typedef __attribute__((ext_vector_type(4))) float f32x4;
typedef __attribute__((ext_vector_type(8))) short bf16x8;

__device__ __forceinline__ float bf2f(u16 u) {
  union { unsigned int i; float f; } v; v.i = ((unsigned int)u) << 16; return v.f;
}
__device__ __forceinline__ u16 f2bf(float f) {
  union { float f; unsigned int i; } v; v.f = f;
  unsigned int u = v.i;
  return (u16)((u + 0x7FFFu + ((u >> 16) & 1u)) >> 16);  // RN-even
}

// async global->LDS, 16B per lane; LDS dest is wave-uniform base + lane*16
__device__ __forceinline__ void gld_lds16(const void* g, void* l) {
  __builtin_amdgcn_global_load_lds(
      (const __attribute__((address_space(1))) unsigned int*)g,
      (__attribute__((address_space(3))) unsigned int*)l,
      16, 0, 0);
}

// ---------------------------------------------------------------------------
// Routing v2: deterministic stable counting sort, latency-optimized.
// 1 block x 1024 threads (16 waves), 16 rounds held ENTIRELY in registers:
//   pass 1: per-(round,wave,expert) counts via ballots -> LDS table (no
//           inter-round dependency, no barriers inside the pass)
//   prefix: 8 threads serially scan 256 entries each (global slot order =
//           (round, wave, lane) = ascending slot index -> stable)
//   pass 2: pos = pbase[c][w][e] + rank_in_wave (saved ballot masks)
// info[0..7]=placed counts (clamped CAP), info[8..15]=segment starts,
// info[16]=total placed rows.
// ---------------------------------------------------------------------------
#define RT_THREADS 1024
#define RT_ROUNDS  (TOTAL_SLOTS / RT_THREADS)   // 16
#define RT_WAVES   (RT_THREADS / 64)            // 16

__global__ __launch_bounds__(RT_THREADS) void k_route(const int* __restrict__ eidx,
                                                      int* __restrict__ info,
                                                      int* __restrict__ row_of_slot,
                                                      int* __restrict__ tok_of_row) {
  __shared__ int s_wcnt[RT_ROUNDS][RT_WAVES][N_EXPERTS];   // 8 KB
  __shared__ int s_pbase[RT_ROUNDS][RT_WAVES][N_EXPERTS];  // 8 KB
  __shared__ int s_start[N_EXPERTS];
  const int t = threadIdx.x, lane = t & 63, w = t >> 6;

  int e[RT_ROUNDS];
  #pragma unroll
  for (int c = 0; c < RT_ROUNDS; ++c) e[c] = eidx[c * RT_THREADS + t];

  unsigned long long mym[RT_ROUNDS];
  #pragma unroll
  for (int c = 0; c < RT_ROUNDS; ++c) {
    unsigned long long mm = 0;
    #pragma unroll
    for (int ee = 0; ee < N_EXPERTS; ++ee) {
      unsigned long long m = __ballot(e[c] == ee);
      if (e[c] == ee) mm = m;
      if (lane == ee) s_wcnt[c][w][ee] = __popcll(m);   // lanes 0..7 store
    }
    mym[c] = mm;
  }
  __syncthreads();

  if (t < N_EXPERTS) {   // exclusive prefix over (round, wave) per expert
    int tot = 0;
    for (int c = 0; c < RT_ROUNDS; ++c)
      for (int ww = 0; ww < RT_WAVES; ++ww) {
        s_pbase[c][ww][t] = tot;
        tot += s_wcnt[c][ww][t];
      }
    s_start[t] = tot;   // expert totals (temporarily)
  }
  __syncthreads();
  if (t == 0) {
    int off = 0;
    for (int ee = 0; ee < N_EXPERTS; ++ee) {
      int tot = s_start[ee];
      int placed = tot < CAP ? tot : CAP;
      info[ee] = placed;
      info[N_EXPERTS + ee] = off;
      s_start[ee] = off;   // now = segment start
      off += placed;
    }
    info[2 * N_EXPERTS] = off;
  }
  __syncthreads();

  #pragma unroll
  for (int c = 0; c < RT_ROUNDS; ++c) {
    const int s = c * RT_THREADS + t;
    const int rank = __popcll(mym[c] & ((1ULL << lane) - 1ULL));
    const int pos = s_pbase[c][w][e[c]] + rank;
    const int row = (pos < CAP) ? (s_start[e[c]] + pos) : -1;
    row_of_slot[s] = row;
    if (row >= 0) tok_of_row[row] = s >> 1;   // token = slot / TOP_K
  }
}

// ---------------------------------------------------------------------------
// Fused per-expert transpose + fp32->bf16 for all three weights in ONE launch.
// z = 0..23: which = z>>3 selects {w1,w2,w3}, e = z&7. Body identical to the
// verified R2 k_transpose; w3 swaps (bx,by) roles to fit the (64,16) grid.
// ---------------------------------------------------------------------------
__global__ __launch_bounds__(256) void k_transpose_all(const float* __restrict__ w1,
                                                       const float* __restrict__ w2,
                                                       const float* __restrict__ w3,
                                                       u16* __restrict__ W1t,
                                                       u16* __restrict__ W2t,
                                                       u16* __restrict__ W3t) {
  __shared__ float tile[64][65];
  const int z = blockIdx.z;
  const int e = z & 7, which = z >> 3;
  const float* in;
  u16* out;
  int R, C, c0, r0;
  if (which == 0)      { in = w1; out = W1t; R = D_MODEL; C = D_FF; }
  else if (which == 1) { in = w2; out = W2t; R = D_MODEL; C = D_FF; }
  else                 { in = w3; out = W3t; R = D_FF;    C = D_MODEL; }
  if (which == 2) { c0 = blockIdx.y * 64; r0 = blockIdx.x * 64; }
  else            { c0 = blockIdx.x * 64; r0 = blockIdx.y * 64; }
  in  += (size_t)e * R * C;
  out += (size_t)e * R * C;
  const int tx = threadIdx.x & 15, ty = threadIdx.x >> 4;

  #pragma unroll
  for (int rr = 0; rr < 4; ++rr) {
    int r = ty + rr * 16;
    float4 v = *(const float4*)&in[(size_t)(r0 + r) * C + c0 + tx * 4];
    tile[r][tx * 4 + 0] = v.x; tile[r][tx * 4 + 1] = v.y;
    tile[r][tx * 4 + 2] = v.z; tile[r][tx * 4 + 3] = v.w;
  }
  __syncthreads();
  #pragma unroll
  for (int rr = 0; rr < 4; ++rr) {
    int oc = ty + rr * 16;
    ushort4 o;
    o.x = f2bf(tile[tx * 4 + 0][oc]);
    o.y = f2bf(tile[tx * 4 + 1][oc]);
    o.z = f2bf(tile[tx * 4 + 2][oc]);
    o.w = f2bf(tile[tx * 4 + 3][oc]);
    *(ushort4*)&out[(size_t)(c0 + oc) * R + r0 + tx * 4] = o;
  }
}

// ---------------------------------------------------------------------------
// Gather dispatched rows of x into compacted bf16 matrix Xd [ROWS_PAD][D_MODEL]
// ---------------------------------------------------------------------------
__global__ __launch_bounds__(256) void k_dispatch(const float* __restrict__ x,
                                                  const int* __restrict__ tok_of_row,
                                                  const int* __restrict__ info,
                                                  u16* __restrict__ Xd) {
  const int r = blockIdx.x;
  const int t = threadIdx.x;
  const int total = info[2 * N_EXPERTS];
  if (r >= total) {
    ushort4 z = {0, 0, 0, 0};
    *(ushort4*)&Xd[(size_t)r * D_MODEL + t * 4] = z;
    return;
  }
  int tok = tok_of_row[r];
  float4 v = *(const float4*)&x[(size_t)tok * D_MODEL + t * 4];
  ushort4 o;
  o.x = f2bf(v.x); o.y = f2bf(v.y); o.z = f2bf(v.z); o.w = f2bf(v.w);
  *(ushort4*)&Xd[(size_t)r * D_MODEL + t * 4] = o;
}

// ---------------------------------------------------------------------------
// FFN pass 1 (fused gate+value): H = silu(Xd @ w1) * (Xd @ w2), bf16 out.
// R2-verbatim (known good): 128x128 tile, BK=64, 4 waves (2x2),
// 16x16x32 bf16 MFMA, global_load_lds staging, XOR chunk swizzle
// (read slot = chunk ^ (row&7), pre-swizzled global source; rule 21).
// ---------------------------------------------------------------------------
__global__ __launch_bounds__(256, 2) void k_ffn1(const u16* __restrict__ Xd,
                                                 const u16* __restrict__ W1t,
                                                 const u16* __restrict__ W2t,
                                                 u16* __restrict__ H,
                                                 const int* __restrict__ info) {
  const int e = blockIdx.z;
  const int count = info[e];
  const int row0 = blockIdx.y * 128;
  if (row0 >= count) return;
  const int start = info[N_EXPERTS + e];
  const int col0 = blockIdx.x * 128;

  __shared__ u16 lsA[128 * 64];
  __shared__ u16 lsB1[128 * 64];
  __shared__ u16 lsB2[128 * 64];

  const int t = threadIdx.x, lane = t & 63, wid = t >> 6;
  const int wr = wid >> 1, wc = wid & 1;

  const u16* gA  = Xd  + (size_t)(start + row0) * D_MODEL;
  const u16* gB1 = W1t + (size_t)e * D_FF * D_MODEL + (size_t)col0 * D_MODEL;
  const u16* gB2 = W2t + (size_t)e * D_FF * D_MODEL + (size_t)col0 * D_MODEL;

  f32x4 accG[4][4] = {};
  f32x4 accV[4][4] = {};

  const int srow = wid * 8 + (lane >> 3);                       // + i*32
  const int skk  = (((lane & 7) ^ ((lane >> 3) & 7)) * 8);
  const int rk0 = (((0 * 4 + (lane >> 4)) ^ (lane & 7)) * 8);   // kk=0
  const int rk1 = (((1 * 4 + (lane >> 4)) ^ (lane & 7)) * 8);   // kk=1

  for (int k0 = 0; k0 < D_MODEL; k0 += 64) {
    __syncthreads();
    #pragma unroll
    for (int i = 0; i < 4; ++i) {
      int r = i * 32 + srow;
      int lbase = (i * 32 + wid * 8) * 64;
      gld_lds16(gA  + (size_t)r * D_MODEL + k0 + skk, &lsA[lbase]);
      gld_lds16(gB1 + (size_t)r * D_MODEL + k0 + skk, &lsB1[lbase]);
      gld_lds16(gB2 + (size_t)r * D_MODEL + k0 + skk, &lsB2[lbase]);
    }
    __syncthreads();   // drains vmcnt -> tiles ready
    #pragma unroll
    for (int kk = 0; kk < 2; ++kk) {
      const int rk = kk ? rk1 : rk0;
      bf16x8 a[4];
      #pragma unroll
      for (int m = 0; m < 4; ++m)
        a[m] = *(const bf16x8*)&lsA[(wr * 64 + m * 16 + (lane & 15)) * 64 + rk];
      #pragma unroll
      for (int n = 0; n < 4; ++n) {
        bf16x8 b1 = *(const bf16x8*)&lsB1[(wc * 64 + n * 16 + (lane & 15)) * 64 + rk];
        bf16x8 b2 = *(const bf16x8*)&lsB2[(wc * 64 + n * 16 + (lane & 15)) * 64 + rk];
        #pragma unroll
        for (int m = 0; m < 4; ++m) {
          accG[m][n] = __builtin_amdgcn_mfma_f32_16x16x32_bf16(a[m], b1, accG[m][n], 0, 0, 0);
          accV[m][n] = __builtin_amdgcn_mfma_f32_16x16x32_bf16(a[m], b2, accV[m][n], 0, 0, 0);
        }
      }
    }
  }

  const int rmax = count - row0;
  const size_t hbase = (size_t)(start + row0);
  #pragma unroll
  for (int m = 0; m < 4; ++m) {
    #pragma unroll
    for (int j = 0; j < 4; ++j) {
      int rit = wr * 64 + m * 16 + (lane >> 4) * 4 + j;  // D: row=(lane>>4)*4+reg
      if (rit < rmax) {
        #pragma unroll
        for (int n = 0; n < 4; ++n) {
          float g = accG[m][n][j];
          float v = accV[m][n][j];
          float h = g * v / (1.0f + __expf(-g));   // silu(g)*v
          H[(hbase + rit) * D_FF + col0 + wc * 64 + n * 16 + (lane & 15)] = f2bf(h);
        }
      }
    }
  }
}

// ---------------------------------------------------------------------------
// FFN pass 2: Y = H @ w3 (B^T layout), bf16 out. R2-verbatim (known good):
// 128x128 tile, BK=64, 4 waves, same staging + swizzle structure.
// ---------------------------------------------------------------------------
__global__ __launch_bounds__(256) void k_ffn2(const u16* __restrict__ Hbuf,
                                              const u16* __restrict__ W3t,
                                              u16* __restrict__ Y,
                                              const int* __restrict__ info) {
  const int e = blockIdx.z;
  const int count = info[e];
  const int row0 = blockIdx.y * 128;
  if (row0 >= count) return;
  const int start = info[N_EXPERTS + e];
  const int col0 = blockIdx.x * 128;

  __shared__ u16 lsA[128 * 64];
  __shared__ u16 lsB[128 * 64];

  const int t = threadIdx.x, lane = t & 63, wid = t >> 6;
  const int wr = wid >> 1, wc = wid & 1;

  const u16* gA = Hbuf + (size_t)(start + row0) * D_FF;
  const u16* gB = W3t + (size_t)e * D_MODEL * D_FF + (size_t)col0 * D_FF;

  f32x4 acc[4][4] = {};

  const int srow = wid * 8 + (lane >> 3);
  const int skk  = (((lane & 7) ^ ((lane >> 3) & 7)) * 8);
  const int rk0 = (((0 * 4 + (lane >> 4)) ^ (lane & 7)) * 8);
  const int rk1 = (((1 * 4 + (lane >> 4)) ^ (lane & 7)) * 8);

  for (int k0 = 0; k0 < D_FF; k0 += 64) {
    __syncthreads();
    #pragma unroll
    for (int i = 0; i < 4; ++i) {
      int r = i * 32 + srow;
      int lbase = (i * 32 + wid * 8) * 64;
      gld_lds16(gA + (size_t)r * D_FF + k0 + skk, &lsA[lbase]);
      gld_lds16(gB + (size_t)r * D_FF + k0 + skk, &lsB[lbase]);
    }
    __syncthreads();
    #pragma unroll
    for (int kk = 0; kk < 2; ++kk) {
      const int rk = kk ? rk1 : rk0;
      bf16x8 a[4];
      #pragma unroll
      for (int m = 0; m < 4; ++m)
        a[m] = *(const bf16x8*)&lsA[(wr * 64 + m * 16 + (lane & 15)) * 64 + rk];
      #pragma unroll
      for (int n = 0; n < 4; ++n) {
        bf16x8 b = *(const bf16x8*)&lsB[(wc * 64 + n * 16 + (lane & 15)) * 64 + rk];
        #pragma unroll
        for (int m = 0; m < 4; ++m)
          acc[m][n] = __builtin_amdgcn_mfma_f32_16x16x32_bf16(a[m], b, acc[m][n], 0, 0, 0);
      }
    }
  }

  const int rmax = count - row0;
  const size_t ybase = (size_t)(start + row0);
  #pragma unroll
  for (int m = 0; m < 4; ++m) {
    #pragma unroll
    for (int j = 0; j < 4; ++j) {
      int rit = wr * 64 + m * 16 + (lane >> 4) * 4 + j;
      if (rit < rmax) {
        #pragma unroll
        for (int n = 0; n < 4; ++n)
          Y[(ybase + rit) * D_MODEL + col0 + wc * 64 + n * 16 + (lane & 15)] = f2bf(acc[m][n][j]);
      }
    }
  }
}

// ---------------------------------------------------------------------------
// Combine: out[t] = sum_k w[t,k] * Y[row(t,k)]   (deterministic k order)
// ---------------------------------------------------------------------------
__global__ __launch_bounds__(256) void k_combine(const u16* __restrict__ Y,
                                                 const int* __restrict__ row_of_slot,
                                                 const float* __restrict__ ew,
                                                 float* __restrict__ out) {
  const int tok = blockIdx.x;
  const int c = threadIdx.x * 4;
  const int r0 = row_of_slot[tok * 2 + 0];
  const int r1 = row_of_slot[tok * 2 + 1];
  const float w0 = ew[tok * 2 + 0];
  const float w1 = ew[tok * 2 + 1];
  float a0 = 0.f, a1 = 0.f, a2 = 0.f, a3 = 0.f;
  if (r0 >= 0) {
    ushort4 y = *(const ushort4*)&Y[(size_t)r0 * D_MODEL + c];
    a0 = w0 * bf2f(y.x); a1 = w0 * bf2f(y.y); a2 = w0 * bf2f(y.z); a3 = w0 * bf2f(y.w);
  }
  if (r1 >= 0) {
    ushort4 y = *(const ushort4*)&Y[(size_t)r1 * D_MODEL + c];
    a0 += w1 * bf2f(y.x); a1 += w1 * bf2f(y.y); a2 += w1 * bf2f(y.z); a3 += w1 * bf2f(y.w);
  }
  float4 o; o.x = a0; o.y = a1; o.z = a2; o.w = a3;
  *(float4*)&out[(size_t)tok * D_MODEL + c] = o;
}

// ---------------------------------------------------------------------------
extern "C" void kernel_launch(void* const* d_in, const int* in_sizes, int n_in,
                              void* d_out, int out_size, void* d_ws, size_t ws_size,
                              hipStream_t stream) {
  const float* x  = (const float*)d_in[0];
  const int*   ei = (const int*)d_in[1];
  const float* ew = (const float*)d_in[2];
  const float* w1 = (const float*)d_in[3];
  const float* w2 = (const float*)d_in[4];
  const float* w3 = (const float*)d_in[5];
  float* out = (float*)d_out;

  char* ws = (char*)d_ws;
  size_t off = 0;
  auto alloc = [&](size_t b) { char* p = ws + off; off += (b + 255) & ~(size_t)255; return p; };
  int* info        = (int*)alloc(256);
  int* row_of_slot = (int*)alloc(sizeof(int) * TOTAL_SLOTS);
  int* tok_of_row  = (int*)alloc(sizeof(int) * ROWS_PAD);
  u16* Xd  = (u16*)alloc((size_t)2 * ROWS_PAD * D_MODEL);
  u16* W1t = (u16*)alloc((size_t)2 * N_EXPERTS * D_FF * D_MODEL);
  u16* W2t = (u16*)alloc((size_t)2 * N_EXPERTS * D_FF * D_MODEL);
  u16* W3t = (u16*)alloc((size_t)2 * N_EXPERTS * D_FF * D_MODEL);
  u16* H   = (u16*)alloc((size_t)2 * ROWS_PAD * D_FF);
  u16* Y   = (u16*)alloc((size_t)2 * ROWS_PAD * D_MODEL);

  k_route<<<1, RT_THREADS, 0, stream>>>(ei, info, row_of_slot, tok_of_row);
  k_transpose_all<<<dim3(64, 16, 24), 256, 0, stream>>>(w1, w2, w3, W1t, W2t, W3t);
  k_dispatch<<<ROWS_PAD, 256, 0, stream>>>(x, tok_of_row, info, Xd);
  k_ffn1<<<dim3(D_FF / 128, CAP / 128, N_EXPERTS), 256, 0, stream>>>(Xd, W1t, W2t, H, info);
  k_ffn2<<<dim3(D_MODEL / 128, CAP / 128, N_EXPERTS), 256, 0, stream>>>(H, W3t, Y, info);
  k_combine<<<N_TOKENS, 256, 0, stream>>>(Y, row_of_slot, ew, out);
}